// Round 11
// baseline (160.151 us; speedup 1.0000x reference)
//
#include <hip/hip_runtime.h>
#include <hip/hip_cooperative_groups.h>

namespace cg = cooperative_groups;

// Pipeline_8400956031319: dual greedy NMS (8192 det + 8192 rpn, IOU>0.6,
// index order) + argmax masking.
//
// R10 rev — ONE cooperative dispatch (R10 had 2; each dispatch costs ~13us
// of gap on this harness; the remaining top dispatches are the harness's own
// 256MB ws-poison fills at ~40us):
//   Phase 1 (per block = (cell,set), 512 blocks x 256 thr): scan the whole
//     input (L2-resident), stage the 3x3 neighborhood of 128px cells in LDS
//     (box size <=120 < 128 => only 3x3 neighborhoods can overlap), run the
//     flattened pair loop, emit edges (i<<13|j, once via orig_a < orig_b)
//     to a PRIVATE per-block global region. Exact ref IOU expression.
//   grid.sync()  (cooperative; __threadfence for cross-XCD visibility)
//   Phase 2: every block redundantly gathers its set's ~3k edges to LDS and
//     runs the Jacobi fixpoint keep[j] = !(exists i<j edge with keep[i])
//     (unique fixpoint == greedy NMS; iterate until stable), then writes its
//     own 32-row slice of the outputs (argmax + masked copies), coalesced.
//   Fallback: if cooperative launch fails (e.g. capture unsupported), run
//     the proven two-kernel R10 path — bit-identical results.

constexpr int NROWS = 8192;
constexpr int NKW   = 256;      // keep words (u32) per set
constexpr unsigned BCAP = 1536; // staged neighborhood cap (mean ~288)
constexpr unsigned ACAP = 512;  // cell-member cap (mean ~32)
constexpr unsigned RCAP = 2048; // per-block edge region cap (mean ~12)
constexpr unsigned ELDS = 8192; // solve-phase LDS edge cache (32 KB)
#define IOU_T 0.6f

// ws layout: cnts[2][256] u32 @ 0 ; edges[2*256][RCAP] u32 @ 4096
constexpr size_t OFF_EDGES = 4096;

// ---------------------------------------------------------------------------
// Shared-memory word layout (reused across phases; 9732 words = 38.9 KB)
//  phase1: Bx1@0  By1@1536 Bx2@3072 By2@4608 Bar@6144 (f32 x1536 each)
//          Bid@7680(1536) aList@9216(512) cw@9728(4: bCnt,aCnt,eCnt,ovf)
//  phase2: eL@0(8192) rcnt@8192(256) roff@8448(256) kbuf@8704(2x256)
//          flags@9216(2: changed parity) Etot@9218  masks@9220(64)
// ---------------------------------------------------------------------------
constexpr int SMW = 9732;

__global__ __launch_bounds__(256) void fused_kernel(
    const float* __restrict__ det, const float* __restrict__ rpn,
    unsigned* __restrict__ cnts, unsigned* __restrict__ edges,
    float* __restrict__ out)
{
  __shared__ unsigned sm[SMW];

  const int blk = blockIdx.x;
  const int cellid = blk & 255;
  const int set    = blk >> 8;
  const int t = threadIdx.x;

  // ---------------- phase 1: scan + pair ----------------
  {
    float*    Bx1 = (float*)&sm[0];
    float*    By1 = (float*)&sm[1536];
    float*    Bx2 = (float*)&sm[3072];
    float*    By2 = (float*)&sm[4608];
    float*    Bar = (float*)&sm[6144];
    unsigned* Bid = &sm[7680];
    unsigned* aList = &sm[9216];
    unsigned* cw = &sm[9728];     // 0:bCnt 1:aCnt 2:eCnt 3:ovf

    const float* src  = (set == 0) ? det : rpn;
    const int    strd = (set == 0) ? 9 : 6;
    unsigned* myedges = edges + ((size_t)(set * 256 + cellid)) * RCAP;
    const int cx = cellid & 15, cy = cellid >> 4;

    if (t < 4) cw[t] = 0u;
    __syncthreads();

    for (int r = t; r < NROWS; r += 256) {
      const float* p = src + (size_t)r * strd + 1;
      const float x1 = p[0], y1 = p[1], x2 = p[2], y2 = p[3];
      const float cxe = 0.5f * (x1 + x2), cye = 0.5f * (y1 + y2);
      const int ccx = min(15, max(0, (int)(cxe * (1.0f / 128.0f))));
      const int ccy = min(15, max(0, (int)(cye * (1.0f / 128.0f))));
      const int dx = ccx - cx, dy = ccy - cy;
      if (dx >= -1 && dx <= 1 && dy >= -1 && dy <= 1) {
        const unsigned s = atomicAdd(&cw[0], 1u);
        if (s < BCAP) {
          Bx1[s] = x1; By1[s] = y1; Bx2[s] = x2; By2[s] = y2;
          Bar[s] = fmaxf(x2 - x1, 0.0f) * fmaxf(y2 - y1, 0.0f); // ref area
          Bid[s] = (unsigned)r;
          if (dx == 0 && dy == 0) {
            const unsigned as = atomicAdd(&cw[1], 1u);
            if (as < ACAP) aList[as] = s; else atomicOr(&cw[3], 1u);
          }
        } else atomicOr(&cw[3], 1u);
      }
    }
    __syncthreads();

    const unsigned nb = min(cw[0], BCAP);
    const unsigned na = min(cw[1], ACAP);

    if (!cw[3]) {
      const unsigned tot = na * nb;            // flattened, independent tests
      for (unsigned p = t; p < tot; p += 256) {
        const unsigned ai = p / nb, x = p - ai * nb;
        const unsigned s = aList[ai];
        const unsigned ia = Bid[s], ib = Bid[x];
        if (ia < ib) {                         // emit-once; skips self
          const float ix1 = fmaxf(Bx1[s], Bx1[x]), iy1 = fmaxf(By1[s], By1[x]);
          const float ix2 = fminf(Bx2[s], Bx2[x]), iy2 = fminf(By2[s], By2[x]);
          const float inter = fmaxf(ix2 - ix1, 0.0f) * fmaxf(iy2 - iy1, 0.0f);
          if (inter > 0.0f) {
            const float uni = Bar[s] + Bar[x] - inter;        // ref order
            const float iou = inter / fmaxf(uni, 1e-9f);      // ref expr
            if (iou > IOU_T) {
              const unsigned slot = atomicAdd(&cw[2], 1u);    // LDS atomic
              if (slot < RCAP) myedges[slot] = (ia << 13) | ib;
            }
          }
        }
      }
    } else {
      // exact fallback (never taken for this data): a = rows in this cell,
      // b = ALL rows; out-of-neighborhood pairs have inter==0 geometrically.
      for (int ra = 0; ra < NROWS; ++ra) {
        const float* pa = src + (size_t)ra * strd + 1;
        const float ax1 = pa[0], ay1 = pa[1], ax2 = pa[2], ay2 = pa[3];
        const float cxe = 0.5f * (ax1 + ax2), cye = 0.5f * (ay1 + ay2);
        const int ccx = min(15, max(0, (int)(cxe * (1.0f / 128.0f))));
        const int ccy = min(15, max(0, (int)(cye * (1.0f / 128.0f))));
        if (ccx != cx || ccy != cy) continue;  // uniform skip
        const float aar = fmaxf(ax2 - ax1, 0.0f) * fmaxf(ay2 - ay1, 0.0f);
        for (int rb = t; rb < NROWS; rb += 256) {
          if ((unsigned)ra >= (unsigned)rb) continue;
          const float* pb = src + (size_t)rb * strd + 1;
          const float bx1 = pb[0], by1 = pb[1], bx2 = pb[2], by2 = pb[3];
          const float ix1 = fmaxf(ax1, bx1), iy1 = fmaxf(ay1, by1);
          const float ix2 = fminf(ax2, bx2), iy2 = fminf(ay2, by2);
          const float inter = fmaxf(ix2 - ix1, 0.0f) * fmaxf(iy2 - iy1, 0.0f);
          if (inter > 0.0f) {
            const float bar = fmaxf(bx2 - bx1, 0.0f) * fmaxf(by2 - by1, 0.0f);
            const float uni = aar + bar - inter;
            const float iou = inter / fmaxf(uni, 1e-9f);
            if (iou > IOU_T) {
              const unsigned slot = atomicAdd(&cw[2], 1u);
              if (slot < RCAP)
                myedges[slot] = ((unsigned)ra << 13) | (unsigned)rb;
            }
          }
        }
      }
    }
    __syncthreads();
    if (t == 0) cnts[set * 256 + cellid] = min(cw[2], RCAP);
  }

  __threadfence();                 // device-scope release (cross-XCD)
  cg::this_grid().sync();          // all edges + counts visible after this

  // ---------------- phase 2: fixpoint + epilogue ----------------
  {
    unsigned* eL    = &sm[0];
    unsigned* rcnt  = &sm[8192];
    unsigned* roff  = &sm[8448];
    unsigned* kb0   = &sm[8704];
    unsigned* kb1   = &sm[8960];
    unsigned* chg   = &sm[9216];   // parity pair
    unsigned* etot  = &sm[9218];
    float*    vmsk  = (float*)&sm[9220];   // 32
    float*    imsk  = (float*)&sm[9252];   // 32

    const unsigned* gedges = edges + (size_t)set * 256 * RCAP;

    if (t < 256) rcnt[t] = min(cnts[set * 256 + t], RCAP);
    __syncthreads();

    // wave0 shuffle-scan of 256 region counts (4/lane)
    if (t < 64) {
      const unsigned h0 = rcnt[4 * t], h1 = rcnt[4 * t + 1];
      const unsigned h2 = rcnt[4 * t + 2], h3 = rcnt[4 * t + 3];
      const unsigned lsum = h0 + h1 + h2 + h3;
      unsigned incl = lsum;
      #pragma unroll
      for (int d = 1; d < 64; d <<= 1) {
        const unsigned v = __shfl_up(incl, d);
        if (t >= d) incl += v;
      }
      const unsigned base = incl - lsum;
      roff[4 * t] = base;               roff[4 * t + 1] = base + h0;
      roff[4 * t + 2] = base + h0 + h1; roff[4 * t + 3] = base + h0 + h1 + h2;
      if (t == 63) *etot = incl;
    }
    if (t < NKW) kb0[t] = 0xFFFFFFFFu;
    __syncthreads();

    const unsigned Etot = *etot;
    const bool cached = (Etot <= ELDS);
    if (cached && t < 256) {              // gather region t's edges (~12)
      const unsigned c = rcnt[t], o = roff[t];
      for (unsigned k = 0; k < c; ++k) eL[o + k] = gedges[(size_t)t * RCAP + k];
    }
    __syncthreads();

    unsigned* kcur = kb0;
    unsigned* knxt = kb1;
    for (int round = 0; round < NROWS + 8; ++round) {
      if (t == 0) chg[round & 1] = 0u;
      if (t < NKW) knxt[t] = 0xFFFFFFFFu;
      __syncthreads();

      if (cached) {
        for (unsigned e = t; e < Etot; e += 256) {
          const unsigned pk = eL[e];
          const unsigned i = pk >> 13, j = pk & 8191u;
          if ((kcur[i >> 5] >> (i & 31)) & 1u)
            atomicAnd(&knxt[j >> 5], ~(1u << (j & 31)));
        }
      } else {                            // exact slow path (never taken)
        for (unsigned r = (unsigned)t >> 2; r < 256u; r += 64u) {
          const unsigned c = rcnt[r];
          for (unsigned k = (unsigned)t & 3u; k < c; k += 4u) {
            const unsigned pk = gedges[(size_t)r * RCAP + k];
            const unsigned i = pk >> 13, j = pk & 8191u;
            if ((kcur[i >> 5] >> (i & 31)) & 1u)
              atomicAnd(&knxt[j >> 5], ~(1u << (j & 31)));
          }
        }
      }
      __syncthreads();

      if (t < NKW && knxt[t] != kcur[t]) chg[round & 1] = 1u;
      __syncthreads();

      unsigned* tmp = kcur; kcur = knxt; knxt = tmp;
      if (!chg[round & 1]) break;  // F(x)==x -> the unique fixpoint
    }

    // epilogue slice: this block writes rows [cellid*32, cellid*32+32)
    const int r0 = cellid * 32;
    if (set == 0) {
      if (t < 32) {
        const int row = r0 + t;
        const bool kd = (kcur[row >> 5] >> (row & 31)) & 1u;
        const float* p = det + (size_t)row * 9;
        const float sc0 = p[5], sc1 = p[6], sc2 = p[7], sc3 = p[8];
        int am = 0; float best = sc0;
        if (sc1 > best) { best = sc1; am = 1; }  // first-max (jnp.argmax)
        if (sc2 > best) { best = sc2; am = 2; }
        if (sc3 > best) { best = sc3; am = 3; }
        vmsk[t] = (kd && am != 0) ? 1.0f : 0.0f;
        imsk[t] = (kd && am == 0) ? 1.0f : 0.0f;
      }
      __syncthreads();
      const size_t f0 = (size_t)r0 * 9;
      float* o0 = out + f0;
      float* o1 = out + (size_t)NROWS * 9 + f0;
      for (int k = t; k < 32 * 9; k += 256) {
        const int lr = k / 9;
        const float v = det[f0 + k];
        o0[k] = v * vmsk[lr];
        o1[k] = v * imsk[lr];
      }
    } else {
      if (t < 32) {
        const int row = r0 + t;
        const bool kr = (kcur[row >> 5] >> (row & 31)) & 1u;
        vmsk[t] = kr ? 1.0f : 0.0f;
      }
      __syncthreads();
      const size_t g0 = (size_t)r0 * 6;
      float* o2 = out + (size_t)NROWS * 18 + g0;
      for (int k = t; k < 32 * 6; k += 256) {
        o2[k] = rpn[g0 + k] * vmsk[k / 6];
      }
    }
  }
}

// ===========================================================================
// Fallback path (bit-identical results): the proven R10 two-kernel pipeline.
// Used only if the cooperative launch is rejected (e.g. by graph capture).
// ===========================================================================
__global__ __launch_bounds__(256) void scanpair_kernel(
    const float* __restrict__ det, const float* __restrict__ rpn,
    unsigned* __restrict__ cnts, unsigned* __restrict__ edges)
{
  const int cellid = blockIdx.x, set = blockIdx.y;
  const float* src  = (set == 0) ? det : rpn;
  const int    strd = (set == 0) ? 9 : 6;
  unsigned* myedges = edges + ((size_t)(set * 256 + cellid)) * RCAP;
  const int cx = cellid & 15, cy = cellid >> 4;

  __shared__ float Bx1[BCAP], By1[BCAP], Bx2[BCAP], By2[BCAP], Bar[BCAP];
  __shared__ unsigned Bid[BCAP];
  __shared__ unsigned aList[ACAP];
  __shared__ unsigned bCnt, aCnt, eCnt, ovf;

  const int t = threadIdx.x;
  if (t == 0) { bCnt = 0u; aCnt = 0u; eCnt = 0u; ovf = 0u; }
  __syncthreads();

  for (int r = t; r < NROWS; r += 256) {
    const float* p = src + (size_t)r * strd + 1;
    const float x1 = p[0], y1 = p[1], x2 = p[2], y2 = p[3];
    const float cxe = 0.5f * (x1 + x2), cye = 0.5f * (y1 + y2);
    const int ccx = min(15, max(0, (int)(cxe * (1.0f / 128.0f))));
    const int ccy = min(15, max(0, (int)(cye * (1.0f / 128.0f))));
    const int dx = ccx - cx, dy = ccy - cy;
    if (dx >= -1 && dx <= 1 && dy >= -1 && dy <= 1) {
      const unsigned s = atomicAdd(&bCnt, 1u);
      if (s < BCAP) {
        Bx1[s] = x1; By1[s] = y1; Bx2[s] = x2; By2[s] = y2;
        Bar[s] = fmaxf(x2 - x1, 0.0f) * fmaxf(y2 - y1, 0.0f);
        Bid[s] = (unsigned)r;
        if (dx == 0 && dy == 0) {
          const unsigned as = atomicAdd(&aCnt, 1u);
          if (as < ACAP) aList[as] = s; else atomicOr(&ovf, 1u);
        }
      } else atomicOr(&ovf, 1u);
    }
  }
  __syncthreads();

  const unsigned nb = min(bCnt, BCAP);
  const unsigned na = min(aCnt, ACAP);

  if (!ovf) {
    const unsigned tot = na * nb;
    for (unsigned p = t; p < tot; p += 256) {
      const unsigned ai = p / nb, x = p - ai * nb;
      const unsigned s = aList[ai];
      const unsigned ia = Bid[s], ib = Bid[x];
      if (ia < ib) {
        const float ix1 = fmaxf(Bx1[s], Bx1[x]), iy1 = fmaxf(By1[s], By1[x]);
        const float ix2 = fminf(Bx2[s], Bx2[x]), iy2 = fminf(By2[s], By2[x]);
        const float inter = fmaxf(ix2 - ix1, 0.0f) * fmaxf(iy2 - iy1, 0.0f);
        if (inter > 0.0f) {
          const float uni = Bar[s] + Bar[x] - inter;
          const float iou = inter / fmaxf(uni, 1e-9f);
          if (iou > IOU_T) {
            const unsigned slot = atomicAdd(&eCnt, 1u);
            if (slot < RCAP) myedges[slot] = (ia << 13) | ib;
          }
        }
      }
    }
  } else {
    for (int ra = 0; ra < NROWS; ++ra) {
      const float* pa = src + (size_t)ra * strd + 1;
      const float ax1 = pa[0], ay1 = pa[1], ax2 = pa[2], ay2 = pa[3];
      const float cxe = 0.5f * (ax1 + ax2), cye = 0.5f * (ay1 + ay2);
      const int ccx = min(15, max(0, (int)(cxe * (1.0f / 128.0f))));
      const int ccy = min(15, max(0, (int)(cye * (1.0f / 128.0f))));
      if (ccx != cx || ccy != cy) continue;
      const float aar = fmaxf(ax2 - ax1, 0.0f) * fmaxf(ay2 - ay1, 0.0f);
      for (int rb = t; rb < NROWS; rb += 256) {
        if ((unsigned)ra >= (unsigned)rb) continue;
        const float* pb = src + (size_t)rb * strd + 1;
        const float bx1 = pb[0], by1 = pb[1], bx2 = pb[2], by2 = pb[3];
        const float ix1 = fmaxf(ax1, bx1), iy1 = fmaxf(ay1, by1);
        const float ix2 = fminf(ax2, bx2), iy2 = fminf(ay2, by2);
        const float inter = fmaxf(ix2 - ix1, 0.0f) * fmaxf(iy2 - iy1, 0.0f);
        if (inter > 0.0f) {
          const float bar = fmaxf(bx2 - bx1, 0.0f) * fmaxf(by2 - by1, 0.0f);
          const float uni = aar + bar - inter;
          const float iou = inter / fmaxf(uni, 1e-9f);
          if (iou > IOU_T) {
            const unsigned slot = atomicAdd(&eCnt, 1u);
            if (slot < RCAP) myedges[slot] = ((unsigned)ra << 13) | (unsigned)rb;
          }
        }
      }
    }
  }
  __syncthreads();
  if (t == 0) cnts[set * 256 + cellid] = min(eCnt, RCAP);
}

__global__ __launch_bounds__(1024) void solve_epi_kernel(
    const float* __restrict__ det, const float* __restrict__ rpn,
    const unsigned* __restrict__ cnts, const unsigned* __restrict__ edges,
    float* __restrict__ out)
{
  const int blk = blockIdx.x;
  const int set = blk >> 4;
  const int slice = blk & 15;
  const unsigned* gedges = edges + (size_t)set * 256 * RCAP;

  __shared__ unsigned eL[16384];
  __shared__ unsigned rcnt[256], roff[256];
  __shared__ unsigned kbuf[2][NKW];
  __shared__ int changed[2];
  __shared__ unsigned Etot_sh;

  const int t = threadIdx.x;
  if (t < 256) rcnt[t] = min(cnts[set * 256 + t], RCAP);
  __syncthreads();

  if (t < 64) {
    const unsigned h0 = rcnt[4 * t], h1 = rcnt[4 * t + 1];
    const unsigned h2 = rcnt[4 * t + 2], h3 = rcnt[4 * t + 3];
    const unsigned lsum = h0 + h1 + h2 + h3;
    unsigned incl = lsum;
    #pragma unroll
    for (int d = 1; d < 64; d <<= 1) {
      const unsigned v = __shfl_up(incl, d);
      if (t >= d) incl += v;
    }
    const unsigned base = incl - lsum;
    roff[4 * t] = base;               roff[4 * t + 1] = base + h0;
    roff[4 * t + 2] = base + h0 + h1; roff[4 * t + 3] = base + h0 + h1 + h2;
    if (t == 63) Etot_sh = incl;
  }
  if (t < NKW) kbuf[0][t] = 0xFFFFFFFFu;
  __syncthreads();

  const unsigned Etot = Etot_sh;
  const bool cached = (Etot <= 16384u);
  if (cached && t < 256) {
    const unsigned c = rcnt[t], o = roff[t];
    for (unsigned k = 0; k < c; ++k) eL[o + k] = gedges[(size_t)t * RCAP + k];
  }
  __syncthreads();

  int cur = 0;
  for (int round = 0; round < NROWS + 8; ++round) {
    const int nxt = cur ^ 1;
    if (t == 0) changed[round & 1] = 0;
    if (t < NKW) kbuf[nxt][t] = 0xFFFFFFFFu;
    __syncthreads();

    if (cached) {
      for (unsigned e = t; e < Etot; e += 1024) {
        const unsigned pk = eL[e];
        const unsigned i = pk >> 13, j = pk & 8191u;
        if ((kbuf[cur][i >> 5] >> (i & 31)) & 1u)
          atomicAnd(&kbuf[nxt][j >> 5], ~(1u << (j & 31)));
      }
    } else {
      for (unsigned r = (unsigned)t >> 2; r < 256u; r += 256u) {
        const unsigned c = rcnt[r];
        for (unsigned k = (unsigned)t & 3u; k < c; k += 4u) {
          const unsigned pk = gedges[(size_t)r * RCAP + k];
          const unsigned i = pk >> 13, j = pk & 8191u;
          if ((kbuf[cur][i >> 5] >> (i & 31)) & 1u)
            atomicAnd(&kbuf[nxt][j >> 5], ~(1u << (j & 31)));
        }
      }
    }
    __syncthreads();

    if (t < NKW && kbuf[nxt][t] != kbuf[cur][t]) changed[round & 1] = 1;
    __syncthreads();

    cur = nxt;
    if (!changed[round & 1]) break;
  }

  const int r0 = slice * 512;
  if (set == 0) {
    for (int i = r0 + t; i < r0 + 512; i += 1024) {
      const bool kd = (kbuf[cur][i >> 5] >> (i & 31)) & 1u;
      const float* p = det + (size_t)i * 9;
      const float sc0 = p[5], sc1 = p[6], sc2 = p[7], sc3 = p[8];
      int am = 0; float best = sc0;
      if (sc1 > best) { best = sc1; am = 1; }
      if (sc2 > best) { best = sc2; am = 2; }
      if (sc3 > best) { best = sc3; am = 3; }
      const float vm = (kd && am != 0) ? 1.0f : 0.0f;
      const float im = (kd && am == 0) ? 1.0f : 0.0f;
      float* o0 = out + (size_t)i * 9;
      float* o1 = out + (size_t)NROWS * 9 + (size_t)i * 9;
      #pragma unroll
      for (int c = 0; c < 9; ++c) { const float v = p[c]; o0[c] = v * vm; o1[c] = v * im; }
    }
  } else {
    for (int i = r0 + t; i < r0 + 512; i += 1024) {
      const bool kr = (kbuf[cur][i >> 5] >> (i & 31)) & 1u;
      const float rm = kr ? 1.0f : 0.0f;
      const float* q = rpn + (size_t)i * 6;
      float* o2 = out + (size_t)NROWS * 18 + (size_t)i * 6;
      #pragma unroll
      for (int c = 0; c < 6; ++c) o2[c] = q[c] * rm;
    }
  }
}

// ---------------------------------------------------------------------------
extern "C" void kernel_launch(void* const* d_in, const int* in_sizes, int n_in,
                              void* d_out, int out_size, void* d_ws, size_t ws_size,
                              hipStream_t stream)
{
  const float* det = (const float*)d_in[0];   // 8192 x 9 fp32
  const float* rpn = (const float*)d_in[1];   // 8192 x 6 fp32
  float* out = (float*)d_out;                 // 8192*9 + 8192*9 + 8192*6 fp32

  char* ws = (char*)d_ws;
  unsigned* cnts  = (unsigned*)ws;            // [2][256] u32
  unsigned* edges = (unsigned*)(ws + OFF_EDGES);

  void* args[] = { (void*)&det, (void*)&rpn, (void*)&cnts, (void*)&edges,
                   (void*)&out };
  const hipError_t err = hipLaunchCooperativeKernel(
      (const void*)fused_kernel, dim3(512), dim3(256), args, 0, stream);
  if (err != hipSuccess) {
    // deterministic fallback: proven two-kernel path, bit-identical output
    dim3 g1(256, 2);
    scanpair_kernel<<<g1, 256, 0, stream>>>(det, rpn, cnts, edges);
    solve_epi_kernel<<<32, 1024, 0, stream>>>(det, rpn, cnts, edges, out);
  }
}

// Round 12
// 75.471 us; speedup vs baseline: 2.1220x; 2.1220x over previous
//
#include <hip/hip_runtime.h>

// Pipeline_8400956031319: dual greedy NMS (8192 det + 8192 rpn, IOU>0.6,
// index order) + argmax masking.
//
// R11 rev — back to TWO plain dispatches (cooperative fusion regressed:
// grid.sync + 512x redundant solve cost more than a graph-replayed launch
// gap ~3us). Cost model: total = 40us fixed harness ws-poison fill +
// sum(kernels) + ~3us/gap. Target: scanpair's 43us, which across R6-R10
// pinned at 43-46us for wildly different work => serial global-load
// latency exposure (~32 rolled iterations), not work. Fix = batch loads.
//
//   K1 scanpair (512 blocks x 512 thr, one block per (cell,set)):
//     scan all 8192 rows in 2 batches of 8 rows/thread — all 8 loads
//     issued before any use (8-deep MLP, 2 latency exposures vs 32);
//     stage 3x3 neighborhood of 128px cells in LDS (box <=120 < 128 =>
//     only 3x3 neighborhoods can overlap); flattened pair loop; exact ref
//     IOU; emit edges (i<<13|j, once via orig_a < orig_b) to a private
//     per-block region. No global atomics, no init kernel.
//   K2 solve_epi (32 blocks x 1024): gather set's ~3k edges to LDS
//     (4 threads per region => 3 serial loads, not 12), Jacobi fixpoint
//     keep[j] = !(exists i<j edge with keep[i]) (unique fixpoint == greedy
//     NMS; iterate until stable), then write 512-row output slice.

constexpr int NROWS = 8192;
constexpr int NKW   = 256;      // keep words (u32) per set
constexpr unsigned BCAP = 1536; // staged neighborhood cap (mean ~288)
constexpr unsigned ACAP = 512;  // cell-member cap (mean ~32)
constexpr unsigned RCAP = 2048; // per-block edge region cap (mean ~12)
constexpr unsigned ELDS = 16384;// solve LDS edge cache
#define IOU_T 0.6f

// ws layout: cnts[2][256] u32 @ 0 ; edges[2*256][RCAP] u32 @ 4096
constexpr size_t OFF_EDGES = 4096;

// ---------------------------------------------------------------------------
// K1: fused scan + pair. grid = (256 cells, 2 sets) x 512 threads.
// ---------------------------------------------------------------------------
__global__ __launch_bounds__(512) void scanpair_kernel(
    const float* __restrict__ det, const float* __restrict__ rpn,
    unsigned* __restrict__ cnts, unsigned* __restrict__ edges)
{
  const int cellid = blockIdx.x, set = blockIdx.y;
  const float* src  = (set == 0) ? det : rpn;
  const int    strd = (set == 0) ? 9 : 6;
  unsigned* myedges = edges + ((size_t)(set * 256 + cellid)) * RCAP;
  const int cx = cellid & 15, cy = cellid >> 4;

  __shared__ float Bx1[BCAP], By1[BCAP], Bx2[BCAP], By2[BCAP], Bar[BCAP];
  __shared__ unsigned Bid[BCAP];
  __shared__ unsigned aList[ACAP];
  __shared__ unsigned bCnt, aCnt, eCnt, ovf;

  const int t = threadIdx.x;
  if (t == 0) { bCnt = 0u; aCnt = 0u; eCnt = 0u; ovf = 0u; }
  __syncthreads();

  // scan: 16 rows/thread, 2 batches of 8. Loads for a whole batch are
  // issued before any consumption -> 8-deep MLP, 2 latency exposures.
  #pragma unroll
  for (int base = 0; base < 16; base += 8) {
    float rx1[8], ry1[8], rx2[8], ry2[8];
    #pragma unroll
    for (int k = 0; k < 8; ++k) {
      const int r = t + (base + k) * 512;
      const float* p = src + (size_t)r * strd + 1;
      rx1[k] = p[0]; ry1[k] = p[1]; rx2[k] = p[2]; ry2[k] = p[3];
    }
    #pragma unroll
    for (int k = 0; k < 8; ++k) {
      const int r = t + (base + k) * 512;
      const float x1 = rx1[k], y1 = ry1[k], x2 = rx2[k], y2 = ry2[k];
      const float cxe = 0.5f * (x1 + x2), cye = 0.5f * (y1 + y2);
      const int ccx = min(15, max(0, (int)(cxe * (1.0f / 128.0f))));
      const int ccy = min(15, max(0, (int)(cye * (1.0f / 128.0f))));
      const int dx = ccx - cx, dy = ccy - cy;
      if (dx >= -1 && dx <= 1 && dy >= -1 && dy <= 1) {
        const unsigned s = atomicAdd(&bCnt, 1u);
        if (s < BCAP) {
          Bx1[s] = x1; By1[s] = y1; Bx2[s] = x2; By2[s] = y2;
          Bar[s] = fmaxf(x2 - x1, 0.0f) * fmaxf(y2 - y1, 0.0f); // ref area
          Bid[s] = (unsigned)r;
          if (dx == 0 && dy == 0) {
            const unsigned as = atomicAdd(&aCnt, 1u);
            if (as < ACAP) aList[as] = s; else atomicOr(&ovf, 1u);
          }
        } else atomicOr(&ovf, 1u);
      }
    }
  }
  __syncthreads();

  const unsigned nb = min(bCnt, BCAP);
  const unsigned na = min(aCnt, ACAP);

  if (!ovf) {
    // flattened pair phase: all tests independent, LDS-resident
    const unsigned tot = na * nb;
    for (unsigned p = t; p < tot; p += 512) {
      const unsigned ai = p / nb, x = p - ai * nb;
      const unsigned s = aList[ai];
      const unsigned ia = Bid[s], ib = Bid[x];
      if (ia < ib) {                                   // emit-once; skips self
        const float ix1 = fmaxf(Bx1[s], Bx1[x]), iy1 = fmaxf(By1[s], By1[x]);
        const float ix2 = fminf(Bx2[s], Bx2[x]), iy2 = fminf(By2[s], By2[x]);
        const float inter = fmaxf(ix2 - ix1, 0.0f) * fmaxf(iy2 - iy1, 0.0f);
        if (inter > 0.0f) {
          const float uni = Bar[s] + Bar[x] - inter;          // ref order
          const float iou = inter / fmaxf(uni, 1e-9f);        // ref expr
          if (iou > IOU_T) {
            const unsigned slot = atomicAdd(&eCnt, 1u);       // LDS atomic
            if (slot < RCAP) myedges[slot] = (ia << 13) | ib;
          }
        }
      }
    }
  } else {
    // exact fallback (never taken for this data): a = rows in this cell,
    // b = ALL rows; out-of-neighborhood pairs have inter==0 geometrically,
    // so semantics are identical to the fast path.
    for (int ra = 0; ra < NROWS; ++ra) {
      const float* pa = src + (size_t)ra * strd + 1;
      const float ax1 = pa[0], ay1 = pa[1], ax2 = pa[2], ay2 = pa[3];
      const float cxe = 0.5f * (ax1 + ax2), cye = 0.5f * (ay1 + ay2);
      const int ccx = min(15, max(0, (int)(cxe * (1.0f / 128.0f))));
      const int ccy = min(15, max(0, (int)(cye * (1.0f / 128.0f))));
      if (ccx != cx || ccy != cy) continue;            // uniform skip
      const float aar = fmaxf(ax2 - ax1, 0.0f) * fmaxf(ay2 - ay1, 0.0f);
      for (int rb = t; rb < NROWS; rb += 512) {
        if ((unsigned)ra >= (unsigned)rb) continue;
        const float* pb = src + (size_t)rb * strd + 1;
        const float bx1 = pb[0], by1 = pb[1], bx2 = pb[2], by2 = pb[3];
        const float ix1 = fmaxf(ax1, bx1), iy1 = fmaxf(ay1, by1);
        const float ix2 = fminf(ax2, bx2), iy2 = fminf(ay2, by2);
        const float inter = fmaxf(ix2 - ix1, 0.0f) * fmaxf(iy2 - iy1, 0.0f);
        if (inter > 0.0f) {
          const float bar = fmaxf(bx2 - bx1, 0.0f) * fmaxf(by2 - by1, 0.0f);
          const float uni = aar + bar - inter;
          const float iou = inter / fmaxf(uni, 1e-9f);
          if (iou > IOU_T) {
            const unsigned slot = atomicAdd(&eCnt, 1u);
            if (slot < RCAP) myedges[slot] = ((unsigned)ra << 13) | (unsigned)rb;
          }
        }
      }
    }
  }
  __syncthreads();
  if (t == 0) cnts[set * 256 + cellid] = min(eCnt, RCAP);
}

// ---------------------------------------------------------------------------
// K2: fixpoint + epilogue. grid = 32 blocks x 1024. set = blk>>4; each block
// solves its set's fixpoint (redundantly, ~3k edges) then writes rows
// [slice*512, slice*512+512) of its outputs.
// ---------------------------------------------------------------------------
__global__ __launch_bounds__(1024) void solve_epi_kernel(
    const float* __restrict__ det, const float* __restrict__ rpn,
    const unsigned* __restrict__ cnts, const unsigned* __restrict__ edges,
    float* __restrict__ out)
{
  const int blk = blockIdx.x;
  const int set = blk >> 4;
  const int slice = blk & 15;
  const unsigned* gedges = edges + (size_t)set * 256 * RCAP;

  __shared__ unsigned eL[ELDS];
  __shared__ unsigned rcnt[256], roff[256];
  __shared__ unsigned kbuf[2][NKW];
  __shared__ int changed[2];
  __shared__ unsigned Etot_sh;

  const int t = threadIdx.x;
  if (t < 256) rcnt[t] = min(cnts[set * 256 + t], RCAP);
  __syncthreads();

  // wave0 shuffle-scan of 256 region counts (4/lane)
  if (t < 64) {
    const unsigned h0 = rcnt[4 * t], h1 = rcnt[4 * t + 1];
    const unsigned h2 = rcnt[4 * t + 2], h3 = rcnt[4 * t + 3];
    const unsigned lsum = h0 + h1 + h2 + h3;
    unsigned incl = lsum;
    #pragma unroll
    for (int d = 1; d < 64; d <<= 1) {
      const unsigned v = __shfl_up(incl, d);
      if (t >= d) incl += v;
    }
    const unsigned base = incl - lsum;
    roff[4 * t] = base;               roff[4 * t + 1] = base + h0;
    roff[4 * t + 2] = base + h0 + h1; roff[4 * t + 3] = base + h0 + h1 + h2;
    if (t == 63) Etot_sh = incl;
  }
  if (t < NKW) kbuf[0][t] = 0xFFFFFFFFu;
  __syncthreads();

  const unsigned Etot = Etot_sh;
  const bool cached = (Etot <= ELDS);
  if (cached) {                 // gather: 4 threads per region (~3 loads ea)
    const unsigned rg = (unsigned)t >> 2, ln = (unsigned)t & 3u;
    const unsigned c = rcnt[rg], o = roff[rg];
    for (unsigned k = ln; k < c; k += 4u)
      eL[o + k] = gedges[(size_t)rg * RCAP + k];
  }
  __syncthreads();

  int cur = 0;
  for (int round = 0; round < NROWS + 8; ++round) {
    const int nxt = cur ^ 1;
    if (t == 0) changed[round & 1] = 0;
    if (t < NKW) kbuf[nxt][t] = 0xFFFFFFFFu;
    __syncthreads();

    if (cached) {
      for (unsigned e = t; e < Etot; e += 1024) {
        const unsigned pk = eL[e];
        const unsigned i = pk >> 13, j = pk & 8191u;
        if ((kbuf[cur][i >> 5] >> (i & 31)) & 1u)
          atomicAnd(&kbuf[nxt][j >> 5], ~(1u << (j & 31)));
      }
    } else {                    // exact slow path (never taken)
      for (unsigned r = (unsigned)t >> 2; r < 256u; r += 256u) {
        const unsigned c = rcnt[r];
        for (unsigned k = (unsigned)t & 3u; k < c; k += 4u) {
          const unsigned pk = gedges[(size_t)r * RCAP + k];
          const unsigned i = pk >> 13, j = pk & 8191u;
          if ((kbuf[cur][i >> 5] >> (i & 31)) & 1u)
            atomicAnd(&kbuf[nxt][j >> 5], ~(1u << (j & 31)));
        }
      }
    }
    __syncthreads();

    if (t < NKW && kbuf[nxt][t] != kbuf[cur][t]) changed[round & 1] = 1;
    __syncthreads();

    cur = nxt;
    if (!changed[round & 1]) break;  // F(x)==x -> the unique fixpoint
  }

  // epilogue slice: 512 rows per block
  const int r0 = slice * 512;
  if (set == 0) {
    for (int i = r0 + t; i < r0 + 512; i += 1024) {
      const bool kd = (kbuf[cur][i >> 5] >> (i & 31)) & 1u;
      const float* p = det + (size_t)i * 9;
      const float sc0 = p[5], sc1 = p[6], sc2 = p[7], sc3 = p[8];
      int am = 0; float best = sc0;
      if (sc1 > best) { best = sc1; am = 1; }   // first-max, like jnp.argmax
      if (sc2 > best) { best = sc2; am = 2; }
      if (sc3 > best) { best = sc3; am = 3; }
      const float vm = (kd && am != 0) ? 1.0f : 0.0f;
      const float im = (kd && am == 0) ? 1.0f : 0.0f;
      float* o0 = out + (size_t)i * 9;
      float* o1 = out + (size_t)NROWS * 9 + (size_t)i * 9;
      #pragma unroll
      for (int c = 0; c < 9; ++c) { const float v = p[c]; o0[c] = v * vm; o1[c] = v * im; }
    }
  } else {
    for (int i = r0 + t; i < r0 + 512; i += 1024) {
      const bool kr = (kbuf[cur][i >> 5] >> (i & 31)) & 1u;
      const float rm = kr ? 1.0f : 0.0f;
      const float* q = rpn + (size_t)i * 6;
      float* o2 = out + (size_t)NROWS * 18 + (size_t)i * 6;
      #pragma unroll
      for (int c = 0; c < 6; ++c) o2[c] = q[c] * rm;
    }
  }
}

// ---------------------------------------------------------------------------
extern "C" void kernel_launch(void* const* d_in, const int* in_sizes, int n_in,
                              void* d_out, int out_size, void* d_ws, size_t ws_size,
                              hipStream_t stream)
{
  const float* det = (const float*)d_in[0];   // 8192 x 9 fp32
  const float* rpn = (const float*)d_in[1];   // 8192 x 6 fp32
  float* out = (float*)d_out;                 // 8192*9 + 8192*9 + 8192*6 fp32

  char* ws = (char*)d_ws;
  unsigned* cnts  = (unsigned*)ws;            // [2][256] u32
  unsigned* edges = (unsigned*)(ws + OFF_EDGES);

  dim3 g1(256, 2);
  scanpair_kernel<<<g1, 512, 0, stream>>>(det, rpn, cnts, edges);
  solve_epi_kernel<<<32, 1024, 0, stream>>>(det, rpn, cnts, edges, out);
}